// Round 21
// baseline (87.623 us; speedup 1.0000x reference)
//
#include <hip/hip_runtime.h>

#define F_IN 128
#define H_DIM 64
#define NBUCK_MAX 1024   // buckets of 128 nodes; N <= 131072
#define BCAP 1664        // slots per bucket region; mean 1280, sd 36 -> +10.7 sigma
#define A1S_STRIDE 72    // LDS a1s row stride (shorts); 144B = 16B-aligned, bank-stride 4

typedef short s16x8 __attribute__((ext_vector_type(8)));
typedef float f32x4 __attribute__((ext_vector_type(4)));
typedef float f32x2 __attribute__((ext_vector_type(2)));

union FragU {
    s16x8 s;
    uint4 q;
    unsigned short u[8];
};

__device__ __forceinline__ unsigned short f2bf(float f) {
    unsigned int b = __float_as_uint(f);
    b += 0x7fffu + ((b >> 16) & 1u);
    return (unsigned short)(b >> 16);
}
__device__ __forceinline__ f32x2 up2(unsigned int v) {
    f32x2 r;
    r.x = __uint_as_float(v << 16);
    r.y = __uint_as_float(v & 0xffff0000u);
    return r;
}
__device__ __forceinline__ f32x2 fma2(f32x2 a, f32x2 b, f32x2 c) {
#if __has_builtin(__builtin_elementwise_fma)
    return __builtin_elementwise_fma(a, b, c);
#else
    f32x2 r;
    r.x = fmaf(a.x, b.x, c.x);
    r.y = fmaf(a.y, b.y, c.y);
    return r;
#endif
}

// ---------------- fused W prepack + gcursor init ----------------
__device__ __forceinline__ void prepack_one(const float* __restrict__ W,
                                            unsigned short* __restrict__ wf, int KS, int tid) {
    int lane = tid & 63;
    int grp = tid >> 6;
    int ks = grp % KS;
    int ct = grp / KS;
    int col = ct * 16 + (lane & 15);
    int kbase = ks * 32 + (lane >> 4) * 8;
    FragU f;
#pragma unroll
    for (int j = 0; j < 8; ++j) f.u[j] = f2bf(W[(kbase + j) * H_DIM + col]);
    reinterpret_cast<uint4*>(wf)[tid] = f.q;
}

__global__ __launch_bounds__(256) void prepack_k(const float* __restrict__ W1, const float* __restrict__ W2,
                                                 unsigned short* __restrict__ wf1, unsigned short* __restrict__ wf2,
                                                 int* __restrict__ gcursor) {
    int tid = blockIdx.x * 256 + threadIdx.x;
    if (tid < NBUCK_MAX) gcursor[tid] = tid * BCAP;   // bucket b's region starts at b*BCAP
    if (tid < 4 * 4 * 64) prepack_one(W1, wf1, 4, tid);
    else if (tid < 4 * 4 * 64 + 4 * 2 * 64) prepack_one(W2, wf2, 2, tid - 4 * 4 * 64);
}

// ---------------- MFMA GEMM1: hb = bf16(x @ W1) [N x 128]@[128 x 64] ----------------
__global__ __launch_bounds__(256) void gemm1_k(const float* __restrict__ x,
                                               const unsigned short* __restrict__ wf,
                                               unsigned short* __restrict__ outb, int N) {
    constexpr int KS = F_IN / 32;
    int wv = threadIdx.x >> 6;
    int lane = threadIdx.x & 63;
    int rb = blockIdx.x * 64 + wv * 16;
    int ra = rb + (lane & 15);
    if (ra > N - 1) ra = N - 1;
    int koct = lane >> 4;

    FragU af[KS];
    const float* ap = x + (size_t)ra * F_IN + koct * 8;
#pragma unroll
    for (int ks = 0; ks < KS; ++ks) {
        float4 v0 = *reinterpret_cast<const float4*>(ap + ks * 32);
        float4 v1 = *reinterpret_cast<const float4*>(ap + ks * 32 + 4);
        af[ks].u[0] = f2bf(v0.x); af[ks].u[1] = f2bf(v0.y);
        af[ks].u[2] = f2bf(v0.z); af[ks].u[3] = f2bf(v0.w);
        af[ks].u[4] = f2bf(v1.x); af[ks].u[5] = f2bf(v1.y);
        af[ks].u[6] = f2bf(v1.z); af[ks].u[7] = f2bf(v1.w);
    }

    const uint4* bq = reinterpret_cast<const uint4*>(wf);
    f32x4 acc[4];
#pragma unroll
    for (int ct = 0; ct < 4; ++ct) acc[ct] = (f32x4){0.f, 0.f, 0.f, 0.f};
#pragma unroll
    for (int ct = 0; ct < 4; ++ct) {
#pragma unroll
        for (int ks = 0; ks < KS; ++ks) {
            FragU b;
            b.q = bq[(ct * KS + ks) * 64 + lane];
            acc[ct] = __builtin_amdgcn_mfma_f32_16x16x32_bf16(af[ks].s, b.s, acc[ct], 0, 0, 0);
        }
    }

    int ro_base = rb + (lane >> 4) * 4;
    int col = lane & 15;
#pragma unroll
    for (int ct = 0; ct < 4; ++ct) {
#pragma unroll
        for (int j = 0; j < 4; ++j) {
            int ro = ro_base + j;
            if (ro < N) outb[(size_t)ro * H_DIM + ct * 16 + col] = f2bf(acc[ct][j]);
        }
    }
}

// ---------------- binA (LDS-lite): counting-sort chunk by bucket, grouped write ----------------
// Stages only edge-index (ushort) + global position (int) in LDS; records are
// rebuilt at write-out from L1/L2-hot ei/ew. LDS 42KB -> 3 blocks/CU @512thr.
__global__ __launch_bounds__(512) void binA_k(const int* __restrict__ ei, const float* __restrict__ ew,
                                              int* __restrict__ gcursor,
                                              unsigned long long* __restrict__ stage, int E, int nbuck) {
    __shared__ unsigned short sidx[4096];   // 8 KB
    __shared__ int smeta[4096];             // 16 KB
    __shared__ int cnt[NBUCK_MAX];
    __shared__ int lbase[NBUCK_MAX];
    __shared__ int gbase[NBUCK_MAX];
    __shared__ int cur[NBUCK_MAX];          // 16 KB total for the 4 bucket arrays
    __shared__ int wsum[512];               // 2 KB
    int tid = threadIdx.x;
    int e0 = blockIdx.x * 4096;
    int ecount = min(4096, E - e0);
    for (int i = tid; i < nbuck; i += 512) { cnt[i] = 0; cur[i] = 0; }
    __syncthreads();
    for (int i = tid; i < ecount; i += 512)
        atomicAdd(&cnt[ei[E + e0 + i] >> 7], 1);
    __syncthreads();
    // exclusive scan of cnt -> lbase (2 entries/thread, 512-thread Hillis-Steele)
    int idx2 = tid * 2;
    int c0 = (idx2 < nbuck) ? cnt[idx2] : 0;
    int c1 = (idx2 + 1 < nbuck) ? cnt[idx2 + 1] : 0;
    int mysum = c0 + c1;
    wsum[tid] = mysum;
    __syncthreads();
    for (int off = 1; off < 512; off <<= 1) {
        int add = (tid >= off) ? wsum[tid - off] : 0;
        __syncthreads();
        wsum[tid] += add;
        __syncthreads();
    }
    int run = wsum[tid] - mysum;
    if (idx2 < nbuck) lbase[idx2] = run;
    if (idx2 + 1 < nbuck) lbase[idx2 + 1] = run + c0;
    __syncthreads();
    // reserve range in each bucket's fixed region (gcursor pre-inited to b*BCAP)
    for (int b = tid; b < nbuck; b += 512)
        gbase[b] = cnt[b] ? atomicAdd(&gcursor[b], cnt[b]) : 0;
    __syncthreads();
    // place: record index + global slot, grouped by bucket
    for (int i = tid; i < ecount; i += 512) {
        int b = ei[E + e0 + i] >> 7;
        int off = atomicAdd(&cur[b], 1);
        int pos = lbase[b] + off;
        sidx[pos] = (unsigned short)i;
        smeta[pos] = gbase[b] + off;
    }
    __syncthreads();
    // write-out: rebuild record from (cache-hot) ei/ew; consecutive pos -> grouped stores
    for (int i = tid; i < ecount; i += 512) {
        int e = e0 + sidx[i];
        int s = ei[e];
        int d = ei[E + e];
        unsigned int wb = __float_as_uint(ew[e]);
        unsigned long long rec = ((unsigned long long)(d & 127) << 49)
                               | ((unsigned long long)(unsigned int)s << 32) | wb;
        stage[smeta[i]] = rec;
    }
}

// ---------------- aggsort1: per-bucket {counting sort} + {agg1} + {gemm2+proj} ----------------
__global__ __launch_bounds__(512) void aggsort1_k(const unsigned short* __restrict__ hb,
                                                  const int* __restrict__ gcursor,
                                                  const unsigned long long* __restrict__ stage,
                                                  const unsigned short* __restrict__ wf2,
                                                  const float* __restrict__ Wlin,
                                                  unsigned long long* __restrict__ epack,
                                                  int2* __restrict__ rdeg,
                                                  float4* __restrict__ uz, int N) {
    __shared__ unsigned long long lout[2304];   // 18.4 KB; [0,BCAP) sort staging, then a1s[128][72] bf16
    __shared__ int cnt[128], exc[128], cur[128];
    unsigned short* a1s = reinterpret_cast<unsigned short*>(lout);
    int b = blockIdx.x;
    int tid = threadIdx.x;
    int base = b * BCAP;
    int nb = gcursor[b] - base;
    if (tid < 128) { cnt[tid] = 0; cur[tid] = 0; }
    __syncthreads();
    for (int i = tid; i < nb; i += 512)
        atomicAdd(&cnt[(int)((stage[base + i] >> 49) & 127)], 1);
    __syncthreads();
    if (tid < 128) exc[tid] = cnt[tid];
    __syncthreads();
    for (int off = 1; off < 128; off <<= 1) {
        int add = (tid >= off && tid < 128) ? exc[tid - off] : 0;
        __syncthreads();
        if (tid < 128) exc[tid] += add;
        __syncthreads();
    }
    if (tid < 128) {
        exc[tid] -= cnt[tid];  // exclusive
        int node = b * 128 + tid;
        if (node < N) rdeg[node] = make_int2(base + exc[tid], cnt[tid]);
    }
    __syncthreads();
    for (int i = tid; i < nb; i += 512) {
        unsigned long long v = stage[base + i];
        int dl = (int)((v >> 49) & 127);
        unsigned int src = (unsigned int)((v >> 32) & 0x1FFFF);
        unsigned int wb = (unsigned int)v;
        int pos = exc[dl] + atomicAdd(&cur[dl], 1);
        lout[pos] = ((unsigned long long)wb << 32) | src;
    }
    __syncthreads();
    for (int i = tid; i < nb; i += 512)
        epack[base + i] = lout[i];

    // ---- phase 2: aggregation into registers ----
    int g = tid >> 2;       // node-in-bucket 0..127
    int dimg = tid & 3;     // dims [dimg*16, +16)
    int start = exc[g];
    int cg = cnt[g];        // 0 for out-of-range nodes
    f32x2 acc[8];
#pragma unroll
    for (int q = 0; q < 8; ++q) acc[q] = (f32x2){0.f, 0.f};
    const uint4* hbase = reinterpret_cast<const uint4*>(hb);
    int j = 0;
    for (; j + 1 < cg; j += 2) {
        unsigned long long p0 = lout[start + j];
        unsigned long long p1 = lout[start + j + 1];
        float wa = __uint_as_float((unsigned int)(p0 >> 32));
        float wbv = __uint_as_float((unsigned int)(p1 >> 32));
        f32x2 w2a = {wa, wa};
        f32x2 w2b = {wbv, wbv};
        const uint4* rp0 = hbase + (size_t)(unsigned int)p0 * (H_DIM / 8) + dimg * 2;
        const uint4* rp1 = hbase + (size_t)(unsigned int)p1 * (H_DIM / 8) + dimg * 2;
        uint4 a0 = rp0[0];
        uint4 a1 = rp0[1];
        uint4 b0 = rp1[0];
        uint4 b1 = rp1[1];
        acc[0] = fma2(w2a, up2(a0.x), acc[0]);
        acc[1] = fma2(w2a, up2(a0.y), acc[1]);
        acc[2] = fma2(w2a, up2(a0.z), acc[2]);
        acc[3] = fma2(w2a, up2(a0.w), acc[3]);
        acc[4] = fma2(w2a, up2(a1.x), acc[4]);
        acc[5] = fma2(w2a, up2(a1.y), acc[5]);
        acc[6] = fma2(w2a, up2(a1.z), acc[6]);
        acc[7] = fma2(w2a, up2(a1.w), acc[7]);
        acc[0] = fma2(w2b, up2(b0.x), acc[0]);
        acc[1] = fma2(w2b, up2(b0.y), acc[1]);
        acc[2] = fma2(w2b, up2(b0.z), acc[2]);
        acc[3] = fma2(w2b, up2(b0.w), acc[3]);
        acc[4] = fma2(w2b, up2(b1.x), acc[4]);
        acc[5] = fma2(w2b, up2(b1.y), acc[5]);
        acc[6] = fma2(w2b, up2(b1.z), acc[6]);
        acc[7] = fma2(w2b, up2(b1.w), acc[7]);
    }
    if (j < cg) {
        unsigned long long p0 = lout[start + j];
        float wa = __uint_as_float((unsigned int)(p0 >> 32));
        f32x2 w2a = {wa, wa};
        const uint4* rp0 = hbase + (size_t)(unsigned int)p0 * (H_DIM / 8) + dimg * 2;
        uint4 a0 = rp0[0];
        uint4 a1 = rp0[1];
        acc[0] = fma2(w2a, up2(a0.x), acc[0]);
        acc[1] = fma2(w2a, up2(a0.y), acc[1]);
        acc[2] = fma2(w2a, up2(a0.z), acc[2]);
        acc[3] = fma2(w2a, up2(a0.w), acc[3]);
        acc[4] = fma2(w2a, up2(a1.x), acc[4]);
        acc[5] = fma2(w2a, up2(a1.y), acc[5]);
        acc[6] = fma2(w2a, up2(a1.z), acc[6]);
        acc[7] = fma2(w2a, up2(a1.w), acc[7]);
    }
    unsigned int pk[8];
#pragma unroll
    for (int q = 0; q < 8; ++q)
        pk[q] = (unsigned int)f2bf(fmaxf(acc[q].x, 0.f))
              | ((unsigned int)f2bf(fmaxf(acc[q].y, 0.f)) << 16);
    __syncthreads();   // all lout reads complete before aliasing writes
    {
        uint4* op = reinterpret_cast<uint4*>(a1s + g * A1S_STRIDE + dimg * 16);
        op[0] = make_uint4(pk[0], pk[1], pk[2], pk[3]);
        op[1] = make_uint4(pk[4], pk[5], pk[6], pk[7]);
    }
    __syncthreads();

    // ---- phase 3: gemm2 (A from LDS a1s) + fused projection -> uz ----
    int wv = tid >> 6;          // wave 0..7 -> rows [wv*16, +16)
    int lane = tid & 63;
    int row = wv * 16 + (lane & 15);
    int koct = lane >> 4;
    FragU af[2];
    af[0].q = *reinterpret_cast<const uint4*>(a1s + row * A1S_STRIDE + koct * 8);
    af[1].q = *reinterpret_cast<const uint4*>(a1s + row * A1S_STRIDE + 32 + koct * 8);
    const uint4* bq = reinterpret_cast<const uint4*>(wf2);
    f32x4 zacc[4];
#pragma unroll
    for (int ct = 0; ct < 4; ++ct) zacc[ct] = (f32x4){0.f, 0.f, 0.f, 0.f};
#pragma unroll
    for (int ct = 0; ct < 4; ++ct) {
#pragma unroll
        for (int ks = 0; ks < 2; ++ks) {
            FragU bb;
            bb.q = bq[(ct * 2 + ks) * 64 + lane];
            zacc[ct] = __builtin_amdgcn_mfma_f32_16x16x32_bf16(af[ks].s, bb.s, zacc[ct], 0, 0, 0);
        }
    }
    int c = lane & 15;
    float w0[4], w1[4], w2[4], w3[4];
#pragma unroll
    for (int ct = 0; ct < 4; ++ct) {
        int col = ct * 16 + c;
        w0[ct] = Wlin[col];        // A0
        w1[ct] = Wlin[128 + col];  // A1
        w2[ct] = Wlin[64 + col];   // B0
        w3[ct] = Wlin[192 + col];  // B1
    }
    int ro_base = b * 128 + wv * 16 + (lane >> 4) * 4;
#pragma unroll
    for (int jj = 0; jj < 4; ++jj) {
        float p0 = 0.f, p1 = 0.f, p2 = 0.f, p3 = 0.f;
#pragma unroll
        for (int ct = 0; ct < 4; ++ct) {
            float zv = zacc[ct][jj];
            p0 = fmaf(zv, w0[ct], p0);
            p1 = fmaf(zv, w1[ct], p1);
            p2 = fmaf(zv, w2[ct], p2);
            p3 = fmaf(zv, w3[ct], p3);
        }
#pragma unroll
        for (int m = 1; m < 16; m <<= 1) {
            p0 += __shfl_xor(p0, m);
            p1 += __shfl_xor(p1, m);
            p2 += __shfl_xor(p2, m);
            p3 += __shfl_xor(p3, m);
        }
        int ro = ro_base + jj;
        if (c == 0 && ro < N) uz[ro] = make_float4(p0, p1, p2, p3);
    }
}

// ---------------- aggv: u[n] = sum_j w_j * uz[src_j]  (thread per node, float4) ----------------
__global__ __launch_bounds__(256) void aggv_k(const float4* __restrict__ uz,
                                              const int2* __restrict__ rdeg,
                                              const unsigned long long* __restrict__ epack,
                                              float4* __restrict__ u, int N) {
    int node = blockIdx.x * 256 + threadIdx.x;
    if (node >= N) return;
    int2 rd = rdeg[node];
    int start = rd.x, cnt = rd.y;
    float4 acc = make_float4(0.f, 0.f, 0.f, 0.f);
    int j = 0;
    for (; j + 3 < cnt; j += 4) {
#pragma unroll
        for (int q = 0; q < 4; ++q) {
            unsigned long long p = epack[start + j + q];
            float w = __uint_as_float((unsigned int)(p >> 32));
            float4 v = uz[(unsigned int)p];
            acc.x = fmaf(w, v.x, acc.x);
            acc.y = fmaf(w, v.y, acc.y);
            acc.z = fmaf(w, v.z, acc.z);
            acc.w = fmaf(w, v.w, acc.w);
        }
    }
    for (; j < cnt; ++j) {
        unsigned long long p = epack[start + j];
        float w = __uint_as_float((unsigned int)(p >> 32));
        float4 v = uz[(unsigned int)p];
        acc.x = fmaf(w, v.x, acc.x);
        acc.y = fmaf(w, v.y, acc.y);
        acc.z = fmaf(w, v.z, acc.z);
        acc.w = fmaf(w, v.w, acc.w);
    }
    u[node] = acc;
}

// ---------------- pair decode (2 pairs per thread) ----------------
__global__ __launch_bounds__(256) void pair_k(const float4* __restrict__ u,
                                              const int* __restrict__ pos,  // [2,P] flat
                                              float2* __restrict__ out, int P, int half) {
    int p = blockIdx.x * 256 + threadIdx.x;
    if (p >= half) return;
    int p1 = p + half;
    bool has1 = p1 < P;
    int s0 = pos[p];
    int t0 = pos[P + p];
    int s1 = has1 ? pos[p1] : s0;
    int t1 = has1 ? pos[P + p1] : t0;
    float4 us0 = u[s0];
    float4 ut0 = u[t0];
    float4 us1 = u[s1];
    float4 ut1 = u[t1];
    union { float f[2]; unsigned long long v; } o;
    o.f[0] = us0.x + ut0.z;
    o.f[1] = us0.y + ut0.w;
    __builtin_nontemporal_store(o.v, reinterpret_cast<unsigned long long*>(&out[p]));
    if (has1) {
        o.f[0] = us1.x + ut1.z;
        o.f[1] = us1.y + ut1.w;
        __builtin_nontemporal_store(o.v, reinterpret_cast<unsigned long long*>(&out[p1]));
    }
}

extern "C" void kernel_launch(void* const* d_in, const int* in_sizes, int n_in,
                              void* d_out, int out_size, void* d_ws, size_t ws_size,
                              hipStream_t stream) {
    const float* x    = (const float*)d_in[0];
    const int*   ei   = (const int*)d_in[1];    // [2,E]
    const float* ew   = (const float*)d_in[2];  // [E]
    const int*   pos  = (const int*)d_in[3];    // [2,P]
    const float* W1   = (const float*)d_in[4];  // [128,64]
    const float* W2   = (const float*)d_in[5];  // [64,64]
    const float* Wlin = (const float*)d_in[6];  // [2,128]
    float* out = (float*)d_out;

    const int N = in_sizes[0] / F_IN;      // 100000
    const int E = in_sizes[2];             // 1000000
    const int P = in_sizes[3] / 2;         // 500000
    const int nbuck = (N + 127) / 128;     // 782

    // workspace layout (bytes)
    char* ws = (char*)d_ws;
    const size_t rowBF = (size_t)N * H_DIM * sizeof(unsigned short);  // 12.8 MB
    const size_t regionBytes = (size_t)nbuck * BCAP * 8;              // ~10.4 MB
    unsigned short* hb   = (unsigned short*)ws;                // gemm1 out (bf16)
    float4*         uz   = (float4*)(ws + rowBF);              // N float4
    float4*         u    = uz + N;                             // N float4
    unsigned long long* stage = (unsigned long long*)((char*)(u + N));  // nbuck*BCAP
    unsigned long long* epack = (unsigned long long*)((char*)stage + regionBytes);
    int* gcursor = (int*)((char*)epack + regionBytes);         // NBUCK_MAX
    int2* rdeg   = (int2*)(gcursor + NBUCK_MAX);               // N
    size_t wf_off = (((size_t)((char*)(rdeg + N) - ws)) + 15) & ~(size_t)15;
    unsigned short* wf1 = (unsigned short*)(ws + wf_off);      // 16 KB
    unsigned short* wf2 = wf1 + 4 * 4 * 64 * 8;                // 8 KB

    // weight prepack + gcursor init (single launch)
    prepack_k<<<6, 256, 0, stream>>>(W1, W2, wf1, wf2, gcursor);

    // conv1 matmul (x f32 -> bf16 in-register) -> hb
    gemm1_k<<<(N + 63) / 64, 256, 0, stream>>>(x, wf1, hb, N);

    // binning sort into fixed bucket regions
    binA_k<<<(E + 4095) / 4096, 512, 0, stream>>>(ei, ew, gcursor, stage, E, nbuck);

    // per-bucket sort + agg1 + gemm2 + proj (emits epack/rdeg for aggv, uz)
    aggsort1_k<<<nbuck, 512, 0, stream>>>(hb, gcursor, stage, wf2, Wlin, epack, rdeg, uz, N);
    // agg2 on projected vectors: uz -> u
    aggv_k<<<(N + 255) / 256, 256, 0, stream>>>(uz, rdeg, epack, u, N);
    // pair decode (2 pairs/thread)
    const int half = (P + 1) / 2;
    pair_k<<<(half + 255) / 256, 256, 0, stream>>>(u, pos, (float2*)out, P, half);
}

// Round 22
// 81.990 us; speedup vs baseline: 1.0687x; 1.0687x over previous
//
#include <hip/hip_runtime.h>

#define F_IN 128
#define H_DIM 64
#define NBUCK_MAX 1024   // buckets of 128 nodes; N <= 131072
#define BCAP 1664        // slots per bucket region; mean 1280, sd 36 -> +10.7 sigma
#define A1S_STRIDE 72    // LDS a1s row stride (shorts); 144B = 16B-aligned, bank-stride 4

typedef short s16x8 __attribute__((ext_vector_type(8)));
typedef float f32x4 __attribute__((ext_vector_type(4)));
typedef float f32x2 __attribute__((ext_vector_type(2)));

union FragU {
    s16x8 s;
    uint4 q;
    unsigned short u[8];
};

__device__ __forceinline__ unsigned short f2bf(float f) {
    unsigned int b = __float_as_uint(f);
    b += 0x7fffu + ((b >> 16) & 1u);
    return (unsigned short)(b >> 16);
}
__device__ __forceinline__ f32x2 up2(unsigned int v) {
    f32x2 r;
    r.x = __uint_as_float(v << 16);
    r.y = __uint_as_float(v & 0xffff0000u);
    return r;
}
__device__ __forceinline__ f32x2 fma2(f32x2 a, f32x2 b, f32x2 c) {
#if __has_builtin(__builtin_elementwise_fma)
    return __builtin_elementwise_fma(a, b, c);
#else
    f32x2 r;
    r.x = fmaf(a.x, b.x, c.x);
    r.y = fmaf(a.y, b.y, c.y);
    return r;
#endif
}

// ---------------- MFMA GEMM1 (self-packing) + block-0 side jobs ----------------
// Each block packs W1 -> LDS B-fragments itself (W1 is L2-resident). Block 0
// additionally packs wf2 (global, for aggsort1) and inits gcursor (for binA);
// stream order guarantees both are visible to the later kernels.
__global__ __launch_bounds__(256) void gemm1_k(const float* __restrict__ x,
                                               const float* __restrict__ W1,
                                               const float* __restrict__ W2,
                                               unsigned short* __restrict__ wf2,
                                               int* __restrict__ gcursor,
                                               unsigned short* __restrict__ outb, int N) {
    constexpr int KS = F_IN / 32;
    __shared__ unsigned short w1s[4 * KS * 64 * 8];   // 16 KB of B-fragments
    int tid = threadIdx.x;

    // pack W1 -> LDS (4 fragments per thread)
#pragma unroll
    for (int q = 0; q < 4; ++q) {
        int f = tid + q * 256;
        int lane = f & 63;
        int grp = f >> 6;
        int ks = grp % KS;
        int ct = grp / KS;
        int col = ct * 16 + (lane & 15);
        int kbase = ks * 32 + (lane >> 4) * 8;
        FragU fr;
#pragma unroll
        for (int j = 0; j < 8; ++j) fr.u[j] = f2bf(W1[(kbase + j) * H_DIM + col]);
        reinterpret_cast<uint4*>(w1s)[f] = fr.q;
    }
    if (blockIdx.x == 0) {
        // pack wf2 (KS2=2): 512 fragments, 2 per thread
#pragma unroll
        for (int q = 0; q < 2; ++q) {
            int f = tid + q * 256;
            int lane = f & 63;
            int grp = f >> 6;
            int ks = grp % 2;
            int ct = grp / 2;
            int col = ct * 16 + (lane & 15);
            int kbase = ks * 32 + (lane >> 4) * 8;
            FragU fr;
#pragma unroll
            for (int j = 0; j < 8; ++j) fr.u[j] = f2bf(W2[(kbase + j) * H_DIM + col]);
            reinterpret_cast<uint4*>(wf2)[f] = fr.q;
        }
        // init gcursor
#pragma unroll
        for (int q = 0; q < 4; ++q) {
            int i = tid + q * 256;
            gcursor[i] = i * BCAP;
        }
    }
    __syncthreads();

    int wv = tid >> 6;
    int lane = tid & 63;
    int rb = blockIdx.x * 64 + wv * 16;
    int ra = rb + (lane & 15);
    if (ra > N - 1) ra = N - 1;
    int koct = lane >> 4;

    FragU af[KS];
    const float* ap = x + (size_t)ra * F_IN + koct * 8;
#pragma unroll
    for (int ks = 0; ks < KS; ++ks) {
        float4 v0 = *reinterpret_cast<const float4*>(ap + ks * 32);
        float4 v1 = *reinterpret_cast<const float4*>(ap + ks * 32 + 4);
        af[ks].u[0] = f2bf(v0.x); af[ks].u[1] = f2bf(v0.y);
        af[ks].u[2] = f2bf(v0.z); af[ks].u[3] = f2bf(v0.w);
        af[ks].u[4] = f2bf(v1.x); af[ks].u[5] = f2bf(v1.y);
        af[ks].u[6] = f2bf(v1.z); af[ks].u[7] = f2bf(v1.w);
    }

    const uint4* bq = reinterpret_cast<const uint4*>(w1s);
    f32x4 acc[4];
#pragma unroll
    for (int ct = 0; ct < 4; ++ct) acc[ct] = (f32x4){0.f, 0.f, 0.f, 0.f};
#pragma unroll
    for (int ct = 0; ct < 4; ++ct) {
#pragma unroll
        for (int ks = 0; ks < KS; ++ks) {
            FragU b;
            b.q = bq[(ct * KS + ks) * 64 + lane];
            acc[ct] = __builtin_amdgcn_mfma_f32_16x16x32_bf16(af[ks].s, b.s, acc[ct], 0, 0, 0);
        }
    }

    int ro_base = rb + (lane >> 4) * 4;
    int col = lane & 15;
#pragma unroll
    for (int ct = 0; ct < 4; ++ct) {
#pragma unroll
        for (int j = 0; j < 4; ++j) {
            int ro = ro_base + j;
            if (ro < N) outb[(size_t)ro * H_DIM + ct * 16 + col] = f2bf(acc[ct][j]);
        }
    }
}

// ---------------- binA (LDS-lite): counting-sort chunk by bucket, grouped write ----------------
__global__ __launch_bounds__(512) void binA_k(const int* __restrict__ ei, const float* __restrict__ ew,
                                              int* __restrict__ gcursor,
                                              unsigned long long* __restrict__ stage, int E, int nbuck) {
    __shared__ unsigned short sidx[4096];   // 8 KB
    __shared__ int smeta[4096];             // 16 KB
    __shared__ int cnt[NBUCK_MAX];
    __shared__ int lbase[NBUCK_MAX];
    __shared__ int gbase[NBUCK_MAX];
    __shared__ int cur[NBUCK_MAX];          // 16 KB total for the 4 bucket arrays
    __shared__ int wsum[512];               // 2 KB
    int tid = threadIdx.x;
    int e0 = blockIdx.x * 4096;
    int ecount = min(4096, E - e0);
    for (int i = tid; i < nbuck; i += 512) { cnt[i] = 0; cur[i] = 0; }
    __syncthreads();
    for (int i = tid; i < ecount; i += 512)
        atomicAdd(&cnt[ei[E + e0 + i] >> 7], 1);
    __syncthreads();
    int idx2 = tid * 2;
    int c0 = (idx2 < nbuck) ? cnt[idx2] : 0;
    int c1 = (idx2 + 1 < nbuck) ? cnt[idx2 + 1] : 0;
    int mysum = c0 + c1;
    wsum[tid] = mysum;
    __syncthreads();
    for (int off = 1; off < 512; off <<= 1) {
        int add = (tid >= off) ? wsum[tid - off] : 0;
        __syncthreads();
        wsum[tid] += add;
        __syncthreads();
    }
    int run = wsum[tid] - mysum;
    if (idx2 < nbuck) lbase[idx2] = run;
    if (idx2 + 1 < nbuck) lbase[idx2 + 1] = run + c0;
    __syncthreads();
    for (int b = tid; b < nbuck; b += 512)
        gbase[b] = cnt[b] ? atomicAdd(&gcursor[b], cnt[b]) : 0;
    __syncthreads();
    for (int i = tid; i < ecount; i += 512) {
        int b = ei[E + e0 + i] >> 7;
        int off = atomicAdd(&cur[b], 1);
        int pos = lbase[b] + off;
        sidx[pos] = (unsigned short)i;
        smeta[pos] = gbase[b] + off;
    }
    __syncthreads();
    for (int i = tid; i < ecount; i += 512) {
        int e = e0 + sidx[i];
        int s = ei[e];
        int d = ei[E + e];
        unsigned int wb = __float_as_uint(ew[e]);
        unsigned long long rec = ((unsigned long long)(d & 127) << 49)
                               | ((unsigned long long)(unsigned int)s << 32) | wb;
        stage[smeta[i]] = rec;
    }
}

// ---------------- aggsort1: per-bucket {counting sort} + {agg1} + {gemm2+proj} ----------------
__global__ __launch_bounds__(512) void aggsort1_k(const unsigned short* __restrict__ hb,
                                                  const int* __restrict__ gcursor,
                                                  const unsigned long long* __restrict__ stage,
                                                  const unsigned short* __restrict__ wf2,
                                                  const float* __restrict__ Wlin,
                                                  unsigned long long* __restrict__ epack,
                                                  int2* __restrict__ rdeg,
                                                  float4* __restrict__ uz, int N) {
    __shared__ unsigned long long lout[2304];   // 18.4 KB; [0,BCAP) sort staging, then a1s[128][72] bf16
    __shared__ int cnt[128], exc[128], cur[128];
    unsigned short* a1s = reinterpret_cast<unsigned short*>(lout);
    int b = blockIdx.x;
    int tid = threadIdx.x;
    int base = b * BCAP;
    int nb = gcursor[b] - base;
    if (tid < 128) { cnt[tid] = 0; cur[tid] = 0; }
    __syncthreads();
    for (int i = tid; i < nb; i += 512)
        atomicAdd(&cnt[(int)((stage[base + i] >> 49) & 127)], 1);
    __syncthreads();
    if (tid < 128) exc[tid] = cnt[tid];
    __syncthreads();
    for (int off = 1; off < 128; off <<= 1) {
        int add = (tid >= off && tid < 128) ? exc[tid - off] : 0;
        __syncthreads();
        if (tid < 128) exc[tid] += add;
        __syncthreads();
    }
    if (tid < 128) {
        exc[tid] -= cnt[tid];  // exclusive
        int node = b * 128 + tid;
        if (node < N) rdeg[node] = make_int2(base + exc[tid], cnt[tid]);
    }
    __syncthreads();
    for (int i = tid; i < nb; i += 512) {
        unsigned long long v = stage[base + i];
        int dl = (int)((v >> 49) & 127);
        unsigned int src = (unsigned int)((v >> 32) & 0x1FFFF);
        unsigned int wb = (unsigned int)v;
        int pos = exc[dl] + atomicAdd(&cur[dl], 1);
        lout[pos] = ((unsigned long long)wb << 32) | src;
    }
    __syncthreads();
    for (int i = tid; i < nb; i += 512)
        epack[base + i] = lout[i];

    // ---- phase 2: aggregation into registers ----
    int g = tid >> 2;       // node-in-bucket 0..127
    int dimg = tid & 3;     // dims [dimg*16, +16)
    int start = exc[g];
    int cg = cnt[g];        // 0 for out-of-range nodes
    f32x2 acc[8];
#pragma unroll
    for (int q = 0; q < 8; ++q) acc[q] = (f32x2){0.f, 0.f};
    const uint4* hbase = reinterpret_cast<const uint4*>(hb);
    int j = 0;
    for (; j + 1 < cg; j += 2) {
        unsigned long long p0 = lout[start + j];
        unsigned long long p1 = lout[start + j + 1];
        float wa = __uint_as_float((unsigned int)(p0 >> 32));
        float wbv = __uint_as_float((unsigned int)(p1 >> 32));
        f32x2 w2a = {wa, wa};
        f32x2 w2b = {wbv, wbv};
        const uint4* rp0 = hbase + (size_t)(unsigned int)p0 * (H_DIM / 8) + dimg * 2;
        const uint4* rp1 = hbase + (size_t)(unsigned int)p1 * (H_DIM / 8) + dimg * 2;
        uint4 a0 = rp0[0];
        uint4 a1 = rp0[1];
        uint4 b0 = rp1[0];
        uint4 b1 = rp1[1];
        acc[0] = fma2(w2a, up2(a0.x), acc[0]);
        acc[1] = fma2(w2a, up2(a0.y), acc[1]);
        acc[2] = fma2(w2a, up2(a0.z), acc[2]);
        acc[3] = fma2(w2a, up2(a0.w), acc[3]);
        acc[4] = fma2(w2a, up2(a1.x), acc[4]);
        acc[5] = fma2(w2a, up2(a1.y), acc[5]);
        acc[6] = fma2(w2a, up2(a1.z), acc[6]);
        acc[7] = fma2(w2a, up2(a1.w), acc[7]);
        acc[0] = fma2(w2b, up2(b0.x), acc[0]);
        acc[1] = fma2(w2b, up2(b0.y), acc[1]);
        acc[2] = fma2(w2b, up2(b0.z), acc[2]);
        acc[3] = fma2(w2b, up2(b0.w), acc[3]);
        acc[4] = fma2(w2b, up2(b1.x), acc[4]);
        acc[5] = fma2(w2b, up2(b1.y), acc[5]);
        acc[6] = fma2(w2b, up2(b1.z), acc[6]);
        acc[7] = fma2(w2b, up2(b1.w), acc[7]);
    }
    if (j < cg) {
        unsigned long long p0 = lout[start + j];
        float wa = __uint_as_float((unsigned int)(p0 >> 32));
        f32x2 w2a = {wa, wa};
        const uint4* rp0 = hbase + (size_t)(unsigned int)p0 * (H_DIM / 8) + dimg * 2;
        uint4 a0 = rp0[0];
        uint4 a1 = rp0[1];
        acc[0] = fma2(w2a, up2(a0.x), acc[0]);
        acc[1] = fma2(w2a, up2(a0.y), acc[1]);
        acc[2] = fma2(w2a, up2(a0.z), acc[2]);
        acc[3] = fma2(w2a, up2(a0.w), acc[3]);
        acc[4] = fma2(w2a, up2(a1.x), acc[4]);
        acc[5] = fma2(w2a, up2(a1.y), acc[5]);
        acc[6] = fma2(w2a, up2(a1.z), acc[6]);
        acc[7] = fma2(w2a, up2(a1.w), acc[7]);
    }
    unsigned int pk[8];
#pragma unroll
    for (int q = 0; q < 8; ++q)
        pk[q] = (unsigned int)f2bf(fmaxf(acc[q].x, 0.f))
              | ((unsigned int)f2bf(fmaxf(acc[q].y, 0.f)) << 16);
    __syncthreads();   // all lout reads complete before aliasing writes
    {
        uint4* op = reinterpret_cast<uint4*>(a1s + g * A1S_STRIDE + dimg * 16);
        op[0] = make_uint4(pk[0], pk[1], pk[2], pk[3]);
        op[1] = make_uint4(pk[4], pk[5], pk[6], pk[7]);
    }
    __syncthreads();

    // ---- phase 3: gemm2 (A from LDS a1s) + fused projection -> uz ----
    int wv = tid >> 6;          // wave 0..7 -> rows [wv*16, +16)
    int lane = tid & 63;
    int row = wv * 16 + (lane & 15);
    int koct = lane >> 4;
    FragU af[2];
    af[0].q = *reinterpret_cast<const uint4*>(a1s + row * A1S_STRIDE + koct * 8);
    af[1].q = *reinterpret_cast<const uint4*>(a1s + row * A1S_STRIDE + 32 + koct * 8);
    const uint4* bq = reinterpret_cast<const uint4*>(wf2);
    f32x4 zacc[4];
#pragma unroll
    for (int ct = 0; ct < 4; ++ct) zacc[ct] = (f32x4){0.f, 0.f, 0.f, 0.f};
#pragma unroll
    for (int ct = 0; ct < 4; ++ct) {
#pragma unroll
        for (int ks = 0; ks < 2; ++ks) {
            FragU bb;
            bb.q = bq[(ct * 2 + ks) * 64 + lane];
            zacc[ct] = __builtin_amdgcn_mfma_f32_16x16x32_bf16(af[ks].s, bb.s, zacc[ct], 0, 0, 0);
        }
    }
    int c = lane & 15;
    float w0[4], w1[4], w2[4], w3[4];
#pragma unroll
    for (int ct = 0; ct < 4; ++ct) {
        int col = ct * 16 + c;
        w0[ct] = Wlin[col];        // A0
        w1[ct] = Wlin[128 + col];  // A1
        w2[ct] = Wlin[64 + col];   // B0
        w3[ct] = Wlin[192 + col];  // B1
    }
    int ro_base = b * 128 + wv * 16 + (lane >> 4) * 4;
#pragma unroll
    for (int jj = 0; jj < 4; ++jj) {
        float p0 = 0.f, p1 = 0.f, p2 = 0.f, p3 = 0.f;
#pragma unroll
        for (int ct = 0; ct < 4; ++ct) {
            float zv = zacc[ct][jj];
            p0 = fmaf(zv, w0[ct], p0);
            p1 = fmaf(zv, w1[ct], p1);
            p2 = fmaf(zv, w2[ct], p2);
            p3 = fmaf(zv, w3[ct], p3);
        }
#pragma unroll
        for (int m = 1; m < 16; m <<= 1) {
            p0 += __shfl_xor(p0, m);
            p1 += __shfl_xor(p1, m);
            p2 += __shfl_xor(p2, m);
            p3 += __shfl_xor(p3, m);
        }
        int ro = ro_base + jj;
        if (c == 0 && ro < N) uz[ro] = make_float4(p0, p1, p2, p3);
    }
}

// ---------------- aggv: u[n] = sum_j w_j * uz[src_j]  (thread per node, float4) ----------------
__global__ __launch_bounds__(256) void aggv_k(const float4* __restrict__ uz,
                                              const int2* __restrict__ rdeg,
                                              const unsigned long long* __restrict__ epack,
                                              float4* __restrict__ u, int N) {
    int node = blockIdx.x * 256 + threadIdx.x;
    if (node >= N) return;
    int2 rd = rdeg[node];
    int start = rd.x, cnt = rd.y;
    float4 acc = make_float4(0.f, 0.f, 0.f, 0.f);
    int j = 0;
    for (; j + 3 < cnt; j += 4) {
#pragma unroll
        for (int q = 0; q < 4; ++q) {
            unsigned long long p = epack[start + j + q];
            float w = __uint_as_float((unsigned int)(p >> 32));
            float4 v = uz[(unsigned int)p];
            acc.x = fmaf(w, v.x, acc.x);
            acc.y = fmaf(w, v.y, acc.y);
            acc.z = fmaf(w, v.z, acc.z);
            acc.w = fmaf(w, v.w, acc.w);
        }
    }
    for (; j < cnt; ++j) {
        unsigned long long p = epack[start + j];
        float w = __uint_as_float((unsigned int)(p >> 32));
        float4 v = uz[(unsigned int)p];
        acc.x = fmaf(w, v.x, acc.x);
        acc.y = fmaf(w, v.y, acc.y);
        acc.z = fmaf(w, v.z, acc.z);
        acc.w = fmaf(w, v.w, acc.w);
    }
    u[node] = acc;
}

// ---------------- pair decode (2 pairs per thread) ----------------
__global__ __launch_bounds__(256) void pair_k(const float4* __restrict__ u,
                                              const int* __restrict__ pos,  // [2,P] flat
                                              float2* __restrict__ out, int P, int half) {
    int p = blockIdx.x * 256 + threadIdx.x;
    if (p >= half) return;
    int p1 = p + half;
    bool has1 = p1 < P;
    int s0 = pos[p];
    int t0 = pos[P + p];
    int s1 = has1 ? pos[p1] : s0;
    int t1 = has1 ? pos[P + p1] : t0;
    float4 us0 = u[s0];
    float4 ut0 = u[t0];
    float4 us1 = u[s1];
    float4 ut1 = u[t1];
    union { float f[2]; unsigned long long v; } o;
    o.f[0] = us0.x + ut0.z;
    o.f[1] = us0.y + ut0.w;
    __builtin_nontemporal_store(o.v, reinterpret_cast<unsigned long long*>(&out[p]));
    if (has1) {
        o.f[0] = us1.x + ut1.z;
        o.f[1] = us1.y + ut1.w;
        __builtin_nontemporal_store(o.v, reinterpret_cast<unsigned long long*>(&out[p1]));
    }
}

extern "C" void kernel_launch(void* const* d_in, const int* in_sizes, int n_in,
                              void* d_out, int out_size, void* d_ws, size_t ws_size,
                              hipStream_t stream) {
    const float* x    = (const float*)d_in[0];
    const int*   ei   = (const int*)d_in[1];    // [2,E]
    const float* ew   = (const float*)d_in[2];  // [E]
    const int*   pos  = (const int*)d_in[3];    // [2,P]
    const float* W1   = (const float*)d_in[4];  // [128,64]
    const float* W2   = (const float*)d_in[5];  // [64,64]
    const float* Wlin = (const float*)d_in[6];  // [2,128]
    float* out = (float*)d_out;

    const int N = in_sizes[0] / F_IN;      // 100000
    const int E = in_sizes[2];             // 1000000
    const int P = in_sizes[3] / 2;         // 500000
    const int nbuck = (N + 127) / 128;     // 782

    // workspace layout (bytes)
    char* ws = (char*)d_ws;
    const size_t rowBF = (size_t)N * H_DIM * sizeof(unsigned short);  // 12.8 MB
    const size_t regionBytes = (size_t)nbuck * BCAP * 8;              // ~10.4 MB
    unsigned short* hb   = (unsigned short*)ws;                // gemm1 out (bf16)
    float4*         uz   = (float4*)(ws + rowBF);              // N float4
    float4*         u    = uz + N;                             // N float4
    unsigned long long* stage = (unsigned long long*)((char*)(u + N));  // nbuck*BCAP
    unsigned long long* epack = (unsigned long long*)((char*)stage + regionBytes);
    int* gcursor = (int*)((char*)epack + regionBytes);         // NBUCK_MAX
    int2* rdeg   = (int2*)(gcursor + NBUCK_MAX);               // N
    size_t wf_off = (((size_t)((char*)(rdeg + N) - ws)) + 15) & ~(size_t)15;
    unsigned short* wf2 = (unsigned short*)(ws + wf_off);      // 8 KB

    // conv1 matmul (self-packs W1 into LDS; block 0 packs wf2 + inits gcursor)
    gemm1_k<<<(N + 63) / 64, 256, 0, stream>>>(x, W1, W2, wf2, gcursor, hb, N);

    // binning sort into fixed bucket regions
    binA_k<<<(E + 4095) / 4096, 512, 0, stream>>>(ei, ew, gcursor, stage, E, nbuck);

    // per-bucket sort + agg1 + gemm2 + proj (emits epack/rdeg for aggv, uz)
    aggsort1_k<<<nbuck, 512, 0, stream>>>(hb, gcursor, stage, wf2, Wlin, epack, rdeg, uz, N);
    // agg2 on projected vectors: uz -> u
    aggv_k<<<(N + 255) / 256, 256, 0, stream>>>(uz, rdeg, epack, u, N);
    // pair decode (2 pairs/thread)
    const int half = (P + 1) / 2;
    pair_k<<<(half + 255) / 256, 256, 0, stream>>>(u, pos, (float2*)out, P, half);
}